// Round 9
// baseline (11.336 us; speedup 1.0000x reference)
//
#include <hip/hip_runtime.h>

// DichotomicSolver: per-row root-find of Dm(m)=mean(sigmoid(30(m-x)))-0.5.
// R9: occupancy fix. 2 waves per row (16 elems/lane), 2048 blocks -> 32
// waves/CU (vs 16). Ballot-chain removed: counts are per-lane int adds + one
// DPP reduce. Cross-wave combine via LDS + 3 barriers; <=128-elem band Newton
// runs on wave 0 of each pair (pure VALU DPP reduces).
// Same math as R8: inverse-CDF c0 from n50, band |x-c0|<=1.7 (below-band
// sigmoid == 1.0f bit-exact since 30*(1.7-1.1)=18; above-band < 3e-5 counts),
// 4 bracketed-Newton iters in [c0-1.1, c0+1.1].
// Fallback (block-uniform, never taken for this input): cooperative 16-step
// bisection + 3 clamped Newton across the wave pair.

constexpr int   S_DIM = 2048;
constexpr int   EPL   = S_DIM / 128;           // 16 elements per lane (2 waves/row)
constexpr float KL2E  = 43.280851308343876f;   // 30 * log2(e)
constexpr int   BANDC = 128;                   // band capacity (mean ~70, max ~102)
constexpr float BHW   = 1.7f;                  // band half-width
constexpr float MCL   = 1.1f;                  // Newton bracket half-width
constexpr int   NNEWT = 4;

template<int CTRL, int RMASK>
__device__ __forceinline__ int dpp_add_i(int v) {
    return v + __builtin_amdgcn_update_dpp(0, v, CTRL, RMASK, 0xF, true);
}

// wave64 inclusive +scan (gfx9 row_shr/row_bcast sequence)
__device__ __forceinline__ int wave_iscan_incl(int v) {
    v = dpp_add_i<0x111, 0xF>(v);
    v = dpp_add_i<0x112, 0xF>(v);
    v = dpp_add_i<0x114, 0xF>(v);
    v = dpp_add_i<0x118, 0xF>(v);
    v = dpp_add_i<0x142, 0xA>(v);
    v = dpp_add_i<0x143, 0xC>(v);
    return v;
}

__device__ __forceinline__ int wave_isum(int v) {
    return __builtin_amdgcn_readlane(wave_iscan_incl(v), 63);
}

template<int CTRL>
__device__ __forceinline__ float dpp_add_f(float v) {
    int sh = __builtin_amdgcn_update_dpp(0, __float_as_int(v), CTRL, 0xF, 0xF, true);
    return v + __int_as_float(sh);
}

__device__ __forceinline__ float wave_reduce_bcast(float v) {
    v = dpp_add_f<0x111>(v);
    v = dpp_add_f<0x112>(v);
    v = dpp_add_f<0x114>(v);
    v = dpp_add_f<0x118>(v);
    v = dpp_add_f<0x142>(v);
    v = dpp_add_f<0x143>(v);
    return __int_as_float(__builtin_amdgcn_readlane(__float_as_int(v), 63));
}

__device__ __forceinline__ float sig(float xv, float m) {
    float e = __builtin_amdgcn_exp2f((xv - m) * KL2E);
    return __builtin_amdgcn_rcpf(1.0f + e);
}

__global__ __launch_bounds__(256, 8)
void dicho_kernel(const float* __restrict__ x, float* __restrict__ out, int bs) {
    __shared__ int   icomm[2][2];        // [pair][wave] int totals
    __shared__ int   pcomm[2][2];        // [pair][wave] packed below|nb totals
    __shared__ float scomm[2][2][2];     // fallback S,T exchange
    __shared__ float band[2][BANDC];     // per-pair band

    const int wid  = threadIdx.x >> 6;   // 0..3
    const int lane = threadIdx.x & 63;
    const int pair = wid >> 1;           // 0..1 (row within block)
    const int wv   = wid & 1;            // 0..1 (wave within row)
    int row = blockIdx.x * 2 + pair;
    const bool valid = (row < bs);
    if (!valid) row = bs - 1;            // keep wave alive for barriers

    // Coalesced load: 128 lanes cover the row; 4 x float4 per lane.
    const float4* xr = reinterpret_cast<const float4*>(x + (size_t)row * S_DIM);
    const int li = wv * 64 + lane;       // lane index within the row's 128 lanes
    float xs[EPL];
    #pragma unroll
    for (int j = 0; j < EPL / 4; ++j) {
        float4 v = xr[j * 128 + li];
        xs[4*j+0] = v.x; xs[4*j+1] = v.y; xs[4*j+2] = v.z; xs[4*j+3] = v.w;
    }

    // ---- n50 = count(x < 50): per-lane adds + one int DPP reduce ----
    int c50 = 0;
    #pragma unroll
    for (int j = 0; j < EPL; ++j) c50 += (xs[j] < 50.0f) ? 1 : 0;
    const int w50 = wave_isum(c50);
    if (lane == 0) icomm[pair][wv] = w50;
    __syncthreads();
    const int n50 = icomm[pair][0] + icomm[pair][1];
    float c0 = 50.0f + (float)(S_DIM / 2 - n50) * (100.0f / (float)S_DIM);
    c0 = fminf(100.0f, fmaxf(0.0f, c0));

    // ---- Band membership + in-wave ranks via one packed int DPP scan ----
    const float blo = c0 - BHW, bhi = c0 + BHW;
    int below_l = 0, nb_l = 0;
    #pragma unroll
    for (int j = 0; j < EPL; ++j) {
        below_l += (xs[j] < blo) ? 1 : 0;
        nb_l    += (xs[j] >= blo && xs[j] <= bhi) ? 1 : 0;
    }
    const int packed = (below_l << 16) | nb_l;
    const int pincl  = wave_iscan_incl(packed);
    const int wtot   = __builtin_amdgcn_readlane(pincl, 63);
    if (lane == 0) pcomm[pair][wv] = wtot;
    __syncthreads();
    const int t00 = pcomm[0][0], t01 = pcomm[0][1];
    const int t10 = pcomm[1][0], t11 = pcomm[1][1];
    const int ta = pair ? t10 : t00, tb = pair ? t11 : t01;
    const int belowN = (ta >> 16) + (tb >> 16);
    const int nb0    = ta & 0xffff;
    const int nbtot  = nb0 + (tb & 0xffff);

    const int  b0  = (t00 >> 16) + (t01 >> 16);
    const int  n0  = (t00 & 0xffff) + (t01 & 0xffff);
    const int  b1  = (t10 >> 16) + (t11 >> 16);
    const int  n1  = (t10 & 0xffff) + (t11 & 0xffff);
    const bool ok0 = (n0 <= BANDC) && (b0 < S_DIM/2) && (b0 + n0 > S_DIM/2);
    const bool ok1 = (n1 <= BANDC) && (b1 < S_DIM/2) && (b1 + n1 > S_DIM/2);
    const bool allok = ok0 && ok1;       // block-uniform -> barrier-safe

    if (allok) {
        // Scatter band at exact deterministic ranks (w1 after w0's nb0).
        int k = ((pincl - packed) & 0xffff) + (wv ? nb0 : 0);
        #pragma unroll
        for (int j = 0; j < EPL; ++j) {
            if (xs[j] >= blo && xs[j] <= bhi) band[pair][k++] = xs[j];
        }
        __syncthreads();

        if (wv == 0) {
            // Band in 2 regs/lane; Newton all in-wave (no barriers).
            const bool  v0 = lane < nbtot, v1 = lane + 64 < nbtot;
            const float a0 = band[pair][lane];
            const float a1 = band[pair][lane + 64];
            const float below = (float)belowN;

            float Lb = c0 - MCL, Rb = c0 + MCL, m = c0;
            #pragma unroll
            for (int t = 0; t < NNEWT; ++t) {
                const float r0 = sig(a0, m), r1 = sig(a1, m);
                const float S = (v0 ? r0 : 0.0f) + (v1 ? r1 : 0.0f);
                const float T = (v0 ? r0 * (1.0f - r0) : 0.0f)
                              + (v1 ? r1 * (1.0f - r1) : 0.0f);
                const float Stot = wave_reduce_bcast(S) + below;
                const float Ttot = wave_reduce_bcast(T);
                const float D  = Stot * (1.0f / (float)S_DIM) - 0.5f;
                const float Dp = Ttot * (30.0f / (float)S_DIM);
                if (D > 0.0f) Rb = m; else Lb = m;
                float mn = m - D * __builtin_amdgcn_rcpf(Dp + 1e-20f);
                if (!(mn > Lb && mn < Rb)) mn = (Lb + Rb) * 0.5f;
                m = mn;
            }
            if (valid && lane == 0) out[row] = m;
        }
    } else {
        // ---- Fallback (block-uniform, never taken for this input):
        //      cooperative 16-step bisection + 3 clamped Newton. ----
        float lo = 0.0f, hi = 100.0f;
        #pragma unroll 1
        for (int t = 0; t < 16; ++t) {
            const float c = (lo + hi) * 0.5f;
            int cl = 0;
            #pragma unroll
            for (int j = 0; j < EPL; ++j) cl += (xs[j] < c) ? 1 : 0;
            const int wc = wave_isum(cl);
            if (lane == 0) icomm[pair][wv] = wc;
            __syncthreads();
            const int cnt = icomm[pair][0] + icomm[pair][1];
            __syncthreads();
            if (cnt >= S_DIM / 2) hi = c; else lo = c;
        }
        float m = (lo + hi) * 0.5f;
        #pragma unroll 1
        for (int t = 0; t < 3; ++t) {
            float S = 0.0f, T = 0.0f;
            #pragma unroll
            for (int j = 0; j < EPL; ++j) {
                const float r = sig(xs[j], m);
                S += r;
                T += r * (1.0f - r);
            }
            S = wave_reduce_bcast(S);
            T = wave_reduce_bcast(T);
            if (lane == 0) { scomm[pair][wv][0] = S; scomm[pair][wv][1] = T; }
            __syncthreads();
            const float St = scomm[pair][0][0] + scomm[pair][1][0];
            const float Tt = scomm[pair][0][1] + scomm[pair][1][1];
            __syncthreads();
            const float D  = St * (1.0f / (float)S_DIM) - 0.5f;
            const float Dp = Tt * (30.0f / (float)S_DIM);
            float step = D * __builtin_amdgcn_rcpf(Dp + 1e-12f);
            step = fminf(0.5f, fmaxf(-0.5f, step));
            m -= step;
        }
        if (valid && wv == 0 && lane == 0) out[row] = m;
    }
}

extern "C" void kernel_launch(void* const* d_in, const int* in_sizes, int n_in,
                              void* d_out, int out_size, void* d_ws, size_t ws_size,
                              hipStream_t stream) {
    const float* x = (const float*)d_in[0];
    float* out = (float*)d_out;
    const int bs = out_size;               // 4096 rows, output [bs,1]
    const int blocks = (bs + 1) / 2;       // 2 rows per 256-thread block
    dicho_kernel<<<blocks, 256, 0, stream>>>(x, out, bs);
}

// Round 10
// 10.963 us; speedup vs baseline: 1.0340x; 1.0340x over previous
//
#include <hip/hip_runtime.h>

// DichotomicSolver: per-row root-find of Dm(m)=mean(sigmoid(30(m-x)))-0.5.
// R10: R8's barrier-free per-wave algorithm, repacked as 8 independent waves
// per 512-thread block -> grid = 512 (tests/removes workgroup-dispatch ramp;
// R9 showed occupancy is NOT the limiter). No __syncthreads anywhere; each
// wave owns a private LDS band slice. n50 counting is interleaved with the
// load-unpack loop so counts overlap in-flight loads (per-chunk vmcnt waits).
// Math identical to R8: inverse-CDF c0 from n50; band |x-c0| <= 1.7 (cap 128
// = 2 regs/lane; below-band sigmoid == 1.0f bit-exact since 30*(1.7-1.1)=18;
// above-band < 3e-5 counts); 4 bracketed-Newton iters in [c0-1.1, c0+1.1].
// Per-wave fallback (never taken for this input): 16-step ballot bisection +
// 3 clamped full-width Newton, registers only.

constexpr int   S_DIM = 2048;
constexpr int   EPL   = S_DIM / 64;            // 32 elements per lane
constexpr float KL2E  = 43.280851308343876f;   // 30 * log2(e)
constexpr int   BANDC = 128;                   // band capacity (mean ~70, max ~102)
constexpr float BHW   = 1.7f;                  // band half-width
constexpr float MCL   = 1.1f;                  // Newton bracket half-width
constexpr int   NNEWT = 4;
constexpr int   WPB   = 8;                     // waves (rows) per block

template<int CTRL, int RMASK>
__device__ __forceinline__ int dpp_add_i(int v) {
    return v + __builtin_amdgcn_update_dpp(0, v, CTRL, RMASK, 0xF, true);
}

// wave64 inclusive +scan (gfx9 row_shr/row_bcast sequence)
__device__ __forceinline__ int wave_iscan_incl(int v) {
    v = dpp_add_i<0x111, 0xF>(v);
    v = dpp_add_i<0x112, 0xF>(v);
    v = dpp_add_i<0x114, 0xF>(v);
    v = dpp_add_i<0x118, 0xF>(v);
    v = dpp_add_i<0x142, 0xA>(v);
    v = dpp_add_i<0x143, 0xC>(v);
    return v;
}

template<int CTRL>
__device__ __forceinline__ float dpp_add_f(float v) {
    int sh = __builtin_amdgcn_update_dpp(0, __float_as_int(v), CTRL, 0xF, 0xF, true);
    return v + __int_as_float(sh);
}

// full wave64 sum broadcast (pure VALU DPP + readlane)
__device__ __forceinline__ float wave_reduce_bcast(float v) {
    v = dpp_add_f<0x111>(v);
    v = dpp_add_f<0x112>(v);
    v = dpp_add_f<0x114>(v);
    v = dpp_add_f<0x118>(v);
    v = dpp_add_f<0x142>(v);
    v = dpp_add_f<0x143>(v);
    return __int_as_float(__builtin_amdgcn_readlane(__float_as_int(v), 63));
}

__device__ __forceinline__ float sig(float xv, float m) {
    float e = __builtin_amdgcn_exp2f((xv - m) * KL2E);
    return __builtin_amdgcn_rcpf(1.0f + e);
}

__global__ __launch_bounds__(512)
void dicho_kernel(const float* __restrict__ x, float* __restrict__ out, int bs) {
    __shared__ float band[WPB][BANDC];   // per-wave private slice -> no barriers

    const int wid  = threadIdx.x >> 6;   // 0..7, one row per wave
    const int lane = threadIdx.x & 63;
    const int row  = blockIdx.x * WPB + wid;
    if (row >= bs) return;               // barrier-free -> early return safe

    // Coalesced load (8 x float4/lane); n50 counting interleaved so the
    // compiler can overlap counts with in-flight loads (vmcnt(N) waits).
    const float4* xr = reinterpret_cast<const float4*>(x + (size_t)row * S_DIM);
    float xs[EPL];
    int c50 = 0;
    #pragma unroll
    for (int j = 0; j < EPL / 4; ++j) {
        float4 v = xr[j * 64 + lane];
        xs[4*j+0] = v.x; xs[4*j+1] = v.y; xs[4*j+2] = v.z; xs[4*j+3] = v.w;
        c50 += (v.x < 50.0f) ? 1 : 0;
        c50 += (v.y < 50.0f) ? 1 : 0;
        c50 += (v.z < 50.0f) ? 1 : 0;
        c50 += (v.w < 50.0f) ? 1 : 0;
    }

    // ---- inverse-CDF estimate from n50 (one int DPP reduce) ----
    const int n50 = __builtin_amdgcn_readlane(wave_iscan_incl(c50), 63);
    float c0 = 50.0f + (float)(S_DIM / 2 - n50) * (100.0f / (float)S_DIM);
    c0 = fminf(100.0f, fmaxf(0.0f, c0));

    // ---- Band membership + exact ranks via ONE packed int DPP scan ----
    const float blo = c0 - BHW, bhi = c0 + BHW;
    int below_l = 0, nb_l = 0;
    #pragma unroll
    for (int j = 0; j < EPL; ++j) {
        below_l += (xs[j] < blo) ? 1 : 0;
        nb_l    += (xs[j] >= blo && xs[j] <= bhi) ? 1 : 0;
    }
    const int packed = (below_l << 16) | nb_l;
    const int pincl  = wave_iscan_incl(packed);
    const int ptot   = __builtin_amdgcn_readlane(pincl, 63);
    const int belowN = ptot >> 16;
    const int nbtot  = ptot & 0xffff;

    float m;
    const bool ok = (nbtot <= BANDC) && (belowN < S_DIM / 2)
                 && (belowN + nbtot > S_DIM / 2);        // wave-uniform
    if (ok) {
        // Scatter band to this wave's LDS slice at exact deterministic ranks.
        int k = (pincl - packed) & 0xffff;
        #pragma unroll
        for (int j = 0; j < EPL; ++j) {
            if (xs[j] >= blo && xs[j] <= bhi) band[wid][k++] = xs[j];
        }
        // Hoist into 2 regs/lane (in-wave DS ordering: no barrier needed).
        const bool  v0 = lane < nbtot, v1 = lane + 64 < nbtot;
        const float a0 = band[wid][lane];
        const float a1 = band[wid][lane + 64];
        const float below = (float)belowN;

        // Bracketed Newton; D monotone increasing in m.
        float Lb = c0 - MCL, Rb = c0 + MCL;
        m = c0;
        #pragma unroll
        for (int t = 0; t < NNEWT; ++t) {
            const float r0 = sig(a0, m), r1 = sig(a1, m);
            const float S = (v0 ? r0 : 0.0f) + (v1 ? r1 : 0.0f);
            const float T = (v0 ? r0 * (1.0f - r0) : 0.0f)
                          + (v1 ? r1 * (1.0f - r1) : 0.0f);
            const float Stot = wave_reduce_bcast(S) + below;
            const float Ttot = wave_reduce_bcast(T);
            const float D  = Stot * (1.0f / (float)S_DIM) - 0.5f;
            const float Dp = Ttot * (30.0f / (float)S_DIM);
            if (D > 0.0f) Rb = m; else Lb = m;
            float mn = m - D * __builtin_amdgcn_rcpf(Dp + 1e-20f);
            if (!(mn > Lb && mn < Rb)) mn = (Lb + Rb) * 0.5f;
            m = mn;
        }
    } else {
        // ---- Fallback (never taken for this input): ballot bisection +
        //      3 clamped full-width Newton, registers only. ----
        float lo = 0.0f, hi = 100.0f;
        #pragma unroll 1
        for (int t = 0; t < 16; ++t) {
            const float c = (lo + hi) * 0.5f;
            int cnt = 0;
            #pragma unroll
            for (int j = 0; j < EPL; ++j)
                cnt += __popcll(__ballot(xs[j] < c));
            if (cnt >= S_DIM / 2) hi = c; else lo = c;
        }
        m = (lo + hi) * 0.5f;
        #pragma unroll 1
        for (int t = 0; t < 3; ++t) {
            float S = 0.0f, T = 0.0f;
            #pragma unroll
            for (int j = 0; j < EPL; ++j) {
                const float r = sig(xs[j], m);
                S += r;
                T += r * (1.0f - r);
            }
            S = wave_reduce_bcast(S);
            T = wave_reduce_bcast(T);
            const float D  = S * (1.0f / (float)S_DIM) - 0.5f;
            const float Dp = T * (30.0f / (float)S_DIM);
            float step = D * __builtin_amdgcn_rcpf(Dp + 1e-12f);
            step = fminf(0.5f, fmaxf(-0.5f, step));
            m -= step;
        }
    }

    if (lane == 0) out[row] = m;
}

extern "C" void kernel_launch(void* const* d_in, const int* in_sizes, int n_in,
                              void* d_out, int out_size, void* d_ws, size_t ws_size,
                              hipStream_t stream) {
    const float* x = (const float*)d_in[0];
    float* out = (float*)d_out;
    const int bs = out_size;                   // 4096 rows, output [bs,1]
    const int blocks = (bs + WPB - 1) / WPB;   // 8 rows per 512-thread block
    dicho_kernel<<<blocks, 512, 0, stream>>>(x, out, bs);
}